// Round 7
// baseline (103.932 us; speedup 1.0000x reference)
//
#include <hip/hip_runtime.h>
#include <hip/hip_bf16.h>
#include <hip/hip_fp16.h>

typedef _Float16 f16;
typedef _Float16 f16x8 __attribute__((ext_vector_type(8)));
typedef float f32x4 __attribute__((ext_vector_type(4)));

#define NB 4
#define SS 2048
#define DD 1024
#define OO 512

// ---- prep: cvt X f32->f16 | transpose-cvt W | zero Ls  (flat grid 4512) ---
__global__ __launch_bounds__(256) void prep(const float* __restrict__ X,
                                            f16* __restrict__ Xh,
                                            const float* __restrict__ w0,
                                            const float* __restrict__ w1,
                                            const float* __restrict__ w2,
                                            f16* __restrict__ Wt,
                                            float* __restrict__ Ls) {
  int b = blockIdx.x;
  int tid = threadIdx.x;
  if (b < 4096) {
    int i = b * 256 + tid;
    const float4* xp = (const float4*)X + (size_t)i * 2;
    float4 a = xp[0], c = xp[1];
    f16x8 v;
    v[0] = (f16)a.x; v[1] = (f16)a.y; v[2] = (f16)a.z; v[3] = (f16)a.w;
    v[4] = (f16)c.x; v[5] = (f16)c.y; v[6] = (f16)c.z; v[7] = (f16)c.w;
    *((f16x8*)Xh + i) = v;
  } else if (b < 4480) {
    int rem = b - 4096;                 // 0..383
    int z = rem >> 7;                   // 0..2
    int rem2 = rem & 127;
    int d0 = (rem2 >> 3) * 64;          // 0..15 -> D blocks
    int o0 = (rem2 & 7) * 64;           // 0..7  -> O blocks
    const float* w = z == 0 ? w0 : (z == 1 ? w1 : w2);
    f16* out = Wt + (size_t)z * OO * DD;
    __shared__ float t[64][65];
#pragma unroll
    for (int i = 0; i < 16; ++i) {
      int idx = i * 256 + tid;
      int r = idx >> 6, c = idx & 63;
      t[r][c] = w[(size_t)(d0 + r) * OO + (o0 + c)];
    }
    __syncthreads();
#pragma unroll
    for (int i = 0; i < 16; ++i) {
      int idx = i * 256 + tid;
      int r = idx >> 6, c = idx & 63;
      out[(size_t)(o0 + r) * DD + (d0 + c)] = (f16)t[c][r];
    }
  } else {
    Ls[(b - 4480) * 256 + tid] = 0.f;
  }
}

// --------------- async global -> LDS, 16B per lane ------------------------
__device__ __forceinline__ void gload_lds16(const f16* g, f16* l) {
  __builtin_amdgcn_global_load_lds(
      (const __attribute__((address_space(1))) void*)g,
      (__attribute__((address_space(3))) void*)l, 16, 0, 0);
}

// counted vmcnt wait: leave fut*LPI loads outstanding (immediates only)
template <int LPI>
__device__ __forceinline__ void wait_fut(int fut) {
  if constexpr (LPI == 6) {
    if (fut >= 2) asm volatile("s_waitcnt vmcnt(12)" ::: "memory");
    else if (fut == 1) asm volatile("s_waitcnt vmcnt(6)" ::: "memory");
    else asm volatile("s_waitcnt vmcnt(0)" ::: "memory");
  } else {  // LPI==8: RING=2
    if (fut >= 1) asm volatile("s_waitcnt vmcnt(8)" ::: "memory");
    else asm volatile("s_waitcnt vmcnt(0)" ::: "memory");
  }
}

// ---- GEMM body, B-transposed: C[m][n] = sum_k A[m][k]*B[n][k] -------------
// TM x 128 tile, BK=64, 256 threads (4 waves). Ring staging (counted vmcnt,
// raw barriers) + XOR-swizzled LDS.  MODE 0: C = (OUT_T)(acc*scale)
template <int TM, int RING, int MODE, typename OUT_T>
__device__ __forceinline__ void gemm_body(const f16* __restrict__ A,
                                          const f16* __restrict__ B,
                                          OUT_T* __restrict__ C,
                                          const float* __restrict__ L, int bm,
                                          int bn, int K, int lda, int ldb,
                                          int ldc, float scale) {
  constexpr int MF = TM / 32;
  constexpr int LPI = TM / 32 + 4;
  constexpr int SLOT = (TM + 128) * 64;
  __shared__ f16 ring[RING * SLOT];

  int tid = threadIdx.x;
  int lane = tid & 63, wid = tid >> 6;
  int wr = (wid >> 1) * (MF * 16), wc = (wid & 1) << 6;
  int r = lane & 15, g = lane >> 4;

  const f16* Ag = A + (long)(bm * TM) * lda;
  const f16* Bg = B + (long)(bn * 128) * ldb;

  int srow = wid * 8 + (lane >> 3);
  int scol = (((lane & 7) ^ ((lane >> 3) & 7)) << 3);

  f32x4 acc[MF][4] = {};
  int nt = K >> 6;

  auto stage = [&](int si, int k0) {
    f16* s = ring + si * SLOT;
#pragma unroll
    for (int i = 0; i < TM / 32; ++i)
      gload_lds16(Ag + (long)(i * 32 + srow) * lda + k0 + scol,
                  s + i * 2048 + wid * 512);
#pragma unroll
    for (int i = 0; i < 4; ++i)
      gload_lds16(Bg + (long)(i * 32 + srow) * ldb + k0 + scol,
                  s + TM * 64 + i * 2048 + wid * 512);
  };

  for (int p = 0; p < RING && p < nt; ++p) stage(p, p * 64);

  int rb = 0;
  for (int t = 0; t < nt; ++t) {
    int fut = nt - 1 - t;
    if (fut > RING - 1) fut = RING - 1;
    wait_fut<LPI>(fut);
    __builtin_amdgcn_s_barrier();
    __builtin_amdgcn_sched_barrier(0);
    const f16* sa = ring + rb * SLOT;
    const f16* sb = sa + TM * 64;
#pragma unroll
    for (int kk = 0; kk < 64; kk += 32) {
      f16x8 af[MF], bf[4];
      int xo = ((kk * 2 + g * 16) ^ ((r & 7) << 4)) >> 1;
#pragma unroll
      for (int m = 0; m < MF; ++m)
        af[m] = *(const f16x8*)&sa[(wr + m * 16 + r) * 64 + xo];
#pragma unroll
      for (int n = 0; n < 4; ++n)
        bf[n] = *(const f16x8*)&sb[(wc + n * 16 + r) * 64 + xo];
#pragma unroll
      for (int m = 0; m < MF; ++m)
#pragma unroll
        for (int n = 0; n < 4; ++n)
          acc[m][n] = __builtin_amdgcn_mfma_f32_16x16x32_f16(af[m], bf[n],
                                                             acc[m][n], 0, 0, 0);
    }
    __builtin_amdgcn_s_barrier();
    __builtin_amdgcn_sched_barrier(0);
    if (t + RING < nt) stage(rb, (t + RING) * 64);
    rb = (rb + 1 == RING) ? 0 : rb + 1;
  }

#pragma unroll
  for (int m = 0; m < MF; ++m)
#pragma unroll
    for (int n = 0; n < 4; ++n)
#pragma unroll
      for (int j = 0; j < 4; ++j) {
        int row = bm * TM + wr + m * 16 + g * 4 + j;
        int col = bn * 128 + wc + n * 16 + r;
        C[(long)row * ldc + col] = (OUT_T)(acc[m][n][j] * scale);
      }
}

// ---- merged QK+V projections: flat grid 768 -------------------------------
__global__ __launch_bounds__(256) void proj_qkv(const f16* __restrict__ Xh,
                                                const f16* __restrict__ Wt,
                                                f16* __restrict__ QKh,
                                                f16* __restrict__ Vt) {
  int id = blockIdx.x;
  if (id < 512) {
    int x = id & 7, j = id >> 3;     // XCD x gets bm in [8x,8x+8), all bn
    int bm = x * 8 + (j >> 3);       // [0,64)
    int bn = j & 7;                  // [0,8)
    gemm_body<128, 2, 0, f16>(Xh, Wt, QKh, nullptr, bm, bn, DD, DD, DD, 1024,
                              1.f);
  } else {
    int vid = id - 512;              // [0,256)
    int x = vid & 7, j = vid >> 3;   // j in [0,32)
    int z = x >> 1;                  // 2 XCDs per batch
    int bn = (x & 1) * 8 + (j >> 2); // [0,16)
    int bm = j & 3;                  // [0,4)
    gemm_body<128, 2, 0, f16>(Wt + 2L * OO * DD, Xh + (long)z * SS * DD,
                              Vt + (long)z * OO * SS, nullptr, bm, bn, DD, DD,
                              DD, SS, 1.f);
  }
}

// ---- scores256: 256x256 tile, 8 waves, 8-phase schedule (T2+T3+T4+T5) -----
__global__ __launch_bounds__(512) void scores256(const f16* __restrict__ QKh,
                                                 f16* __restrict__ P,
                                                 float* __restrict__ L,
                                                 float scale, float shift) {
  int b = blockIdx.x;                // [0,256) flat, XCD = b%8
  int x = b & 7, j = b >> 3;         // j in [0,32)
  int z = x >> 1;                    // 2 XCDs per batch
  int bm = (x & 1) * 4 + (j >> 3);   // [0,8)
  int bn = j & 7;                    // [0,8)

  const f16* A = QKh + (long)z * SS * 1024;        // Q
  const f16* B = QKh + (long)z * SS * 1024 + 512;  // K
  f16* C = P + (long)z * SS * SS;
  float* Ls = L + (long)z * SS;

  __shared__ f16 ring[2 * 32768];  // 128 KB
  int tid = threadIdx.x;
  int lane = tid & 63, wid = tid >> 6;
  int wm = wid >> 2, wn = wid & 3;  // 2M x 4N waves
  int r = lane & 15, g = lane >> 4;

  const f16* Ag = A + (long)(bm * 256) * 1024;
  const f16* Bg = B + (long)(bn * 256) * 1024;

  int srow = tid >> 3;  // 0..63
  int scol = (((tid & 7) ^ ((tid >> 3) & 7)) << 3);

  f32x4 acc[8][4] = {};
  const int nt = 8;  // K=512 / BK=64

  auto stage = [&](int si, int k0) {
    f16* s = ring + si * 32768;
#pragma unroll
    for (int i = 0; i < 4; ++i)
      gload_lds16(Ag + (long)(i * 64 + srow) * 1024 + k0 + scol,
                  s + i * 4096 + tid * 8);
#pragma unroll
    for (int i = 0; i < 4; ++i)
      gload_lds16(Bg + (long)(i * 64 + srow) * 1024 + k0 + scol,
                  s + 16384 + i * 4096 + tid * 8);
  };
  stage(0, 0);
  stage(1, 64);

  int rb = 0;
  int arow = wm * 128 + r, brow = wn * 64 + r;
  for (int t = 0; t < nt; ++t) {
    if (t < nt - 1) asm volatile("s_waitcnt vmcnt(8)" ::: "memory");
    else            asm volatile("s_waitcnt vmcnt(0)" ::: "memory");
    __builtin_amdgcn_s_barrier();
    const f16* sa = ring + rb * 32768;
    const f16* sb = sa + 16384;
    int xo0 = ((g * 16) ^ ((r & 7) << 4)) >> 1;
    int xo1 = ((64 + g * 16) ^ ((r & 7) << 4)) >> 1;
    f16x8 af[4], bf[4];
    // ---- phase 0: m0-3, kk=0 ----
#pragma unroll
    for (int m = 0; m < 4; ++m)
      af[m] = *(const f16x8*)&sa[(arow + m * 16) * 64 + xo0];
#pragma unroll
    for (int n = 0; n < 4; ++n)
      bf[n] = *(const f16x8*)&sb[(brow + n * 16) * 64 + xo0];
    __builtin_amdgcn_s_barrier();
    asm volatile("s_waitcnt lgkmcnt(0)" ::: "memory");
    __builtin_amdgcn_sched_barrier(0);
    __builtin_amdgcn_s_setprio(1);
#pragma unroll
    for (int m = 0; m < 4; ++m)
#pragma unroll
      for (int n = 0; n < 4; ++n)
        acc[m][n] = __builtin_amdgcn_mfma_f32_16x16x32_f16(af[m], bf[n],
                                                           acc[m][n], 0, 0, 0);
    __builtin_amdgcn_s_setprio(0);
    __builtin_amdgcn_s_barrier();
    // ---- phase 1: m4-7, kk=0 ----
#pragma unroll
    for (int m = 0; m < 4; ++m)
      af[m] = *(const f16x8*)&sa[(arow + (m + 4) * 16) * 64 + xo0];
    __builtin_amdgcn_s_barrier();
    asm volatile("s_waitcnt lgkmcnt(0)" ::: "memory");
    __builtin_amdgcn_sched_barrier(0);
    __builtin_amdgcn_s_setprio(1);
#pragma unroll
    for (int m = 0; m < 4; ++m)
#pragma unroll
      for (int n = 0; n < 4; ++n)
        acc[m + 4][n] = __builtin_amdgcn_mfma_f32_16x16x32_f16(
            af[m], bf[n], acc[m + 4][n], 0, 0, 0);
    __builtin_amdgcn_s_setprio(0);
    __builtin_amdgcn_s_barrier();
    // ---- phase 2: m0-3, kk=32 ----
#pragma unroll
    for (int m = 0; m < 4; ++m)
      af[m] = *(const f16x8*)&sa[(arow + m * 16) * 64 + xo1];
#pragma unroll
    for (int n = 0; n < 4; ++n)
      bf[n] = *(const f16x8*)&sb[(brow + n * 16) * 64 + xo1];
    __builtin_amdgcn_s_barrier();
    asm volatile("s_waitcnt lgkmcnt(0)" ::: "memory");
    __builtin_amdgcn_sched_barrier(0);
    __builtin_amdgcn_s_setprio(1);
#pragma unroll
    for (int m = 0; m < 4; ++m)
#pragma unroll
      for (int n = 0; n < 4; ++n)
        acc[m][n] = __builtin_amdgcn_mfma_f32_16x16x32_f16(af[m], bf[n],
                                                           acc[m][n], 0, 0, 0);
    __builtin_amdgcn_s_setprio(0);
    __builtin_amdgcn_s_barrier();
    // ---- phase 3: m4-7, kk=32; stage t+2 after read-complete barrier ----
#pragma unroll
    for (int m = 0; m < 4; ++m)
      af[m] = *(const f16x8*)&sa[(arow + (m + 4) * 16) * 64 + xo1];
    asm volatile("s_waitcnt lgkmcnt(0)" ::: "memory");
    __builtin_amdgcn_sched_barrier(0);
    __builtin_amdgcn_s_barrier();   // all waves done reading slot rb
    if (t + 2 < nt) stage(rb, (t + 2) * 64);
    __builtin_amdgcn_s_setprio(1);
#pragma unroll
    for (int m = 0; m < 4; ++m)
#pragma unroll
      for (int n = 0; n < 4; ++n)
        acc[m + 4][n] = __builtin_amdgcn_mfma_f32_16x16x32_f16(
            af[m], bf[n], acc[m + 4][n], 0, 0, 0);
    __builtin_amdgcn_s_setprio(0);
    __builtin_amdgcn_s_barrier();
    rb ^= 1;
  }

  // epilogue: exp2 + store f16 + rowsum atomics
  float rs[8][4];
#pragma unroll
  for (int m = 0; m < 8; ++m)
#pragma unroll
    for (int jj = 0; jj < 4; ++jj) rs[m][jj] = 0.f;
#pragma unroll
  for (int m = 0; m < 8; ++m)
#pragma unroll
    for (int n = 0; n < 4; ++n)
#pragma unroll
      for (int jj = 0; jj < 4; ++jj) {
        int row = bm * 256 + wm * 128 + m * 16 + g * 4 + jj;
        int col = bn * 256 + wn * 64 + n * 16 + r;
        float e = exp2f(acc[m][n][jj] * scale - shift);
        C[(long)row * SS + col] = (f16)e;
        rs[m][jj] += e;
      }
#pragma unroll
  for (int m = 0; m < 8; ++m)
#pragma unroll
    for (int jj = 0; jj < 4; ++jj) {
      float v = rs[m][jj];
      v += __shfl_xor(v, 1);
      v += __shfl_xor(v, 2);
      v += __shfl_xor(v, 4);
      v += __shfl_xor(v, 8);
      if (r == 0)
        atomicAdd(&Ls[bm * 256 + wm * 128 + m * 16 + g * 4 + jj], v);
    }
}

// ---- pv256: out = (P~ @ V) / L[row].  64x256 tile, 8 waves, phase sched ---
__global__ __launch_bounds__(512) void pv256(const f16* __restrict__ Pb,
                                             const f16* __restrict__ Vt,
                                             float* __restrict__ out,
                                             const float* __restrict__ Ls) {
  int b = blockIdx.x;                // 256 blocks, XCD = b%8
  int x = b & 7, j = b >> 3;         // j in [0,32)
  int z = x >> 1;                    // 2 XCDs per batch
  int bm = (x & 1) * 16 + (j >> 1);  // [0,32)
  int bn = j & 1;                    // [0,2)

  const f16* A = Pb + (long)z * SS * SS;
  const f16* B = Vt + (long)z * OO * SS;
  float* C = out + (long)z * SS * OO;
  const float* L = Ls + (long)z * SS;

  __shared__ f16 ring[2 * 20480];  // 2 x (64+256)*64 f16 = 80 KB
  int tid = threadIdx.x;
  int lane = tid & 63, wid = tid >> 6;
  int wm = wid >> 2, wn = wid & 3;  // 2M x 4N waves; wave owns 32x64
  int r = lane & 15, g = lane >> 4;

  const f16* Ag = A + (long)(bm * 64) * SS;
  const f16* Bg = B + (long)(bn * 256) * SS;

  int srow = tid >> 3;  // 0..63
  int scol = (((tid & 7) ^ ((tid >> 3) & 7)) << 3);

  f32x4 acc[2][4] = {};
  const int nt = SS / 64;  // 32

  auto stage = [&](int si, int k0) {
    f16* s = ring + si * 20480;
    gload_lds16(Ag + (long)srow * SS + k0 + scol, s + tid * 8);
#pragma unroll
    for (int i = 0; i < 4; ++i)
      gload_lds16(Bg + (long)(i * 64 + srow) * SS + k0 + scol,
                  s + 4096 + i * 4096 + tid * 8);
  };
  stage(0, 0);
  stage(1, 64);

  int rb = 0;
  int arow = wm * 32 + r, brow = wn * 64 + r;
  for (int t = 0; t < nt; ++t) {
    if (t < nt - 1) asm volatile("s_waitcnt vmcnt(5)" ::: "memory");
    else            asm volatile("s_waitcnt vmcnt(0)" ::: "memory");
    __builtin_amdgcn_s_barrier();
    const f16* sa = ring + rb * 20480;
    const f16* sb = sa + 4096;
    int xo0 = ((g * 16) ^ ((r & 7) << 4)) >> 1;
    int xo1 = ((64 + g * 16) ^ ((r & 7) << 4)) >> 1;
    f16x8 af[2], bf[4];
    // ---- phase 0: kk=0 ----
#pragma unroll
    for (int m = 0; m < 2; ++m)
      af[m] = *(const f16x8*)&sa[(arow + m * 16) * 64 + xo0];
#pragma unroll
    for (int n = 0; n < 4; ++n)
      bf[n] = *(const f16x8*)&sb[(brow + n * 16) * 64 + xo0];
    __builtin_amdgcn_s_barrier();
    asm volatile("s_waitcnt lgkmcnt(0)" ::: "memory");
    __builtin_amdgcn_sched_barrier(0);
    __builtin_amdgcn_s_setprio(1);
#pragma unroll
    for (int m = 0; m < 2; ++m)
#pragma unroll
      for (int n = 0; n < 4; ++n)
        acc[m][n] = __builtin_amdgcn_mfma_f32_16x16x32_f16(af[m], bf[n],
                                                           acc[m][n], 0, 0, 0);
    __builtin_amdgcn_s_setprio(0);
    __builtin_amdgcn_s_barrier();
    // ---- phase 1: kk=32; stage t+2 after read-complete barrier ----
#pragma unroll
    for (int m = 0; m < 2; ++m)
      af[m] = *(const f16x8*)&sa[(arow + m * 16) * 64 + xo1];
#pragma unroll
    for (int n = 0; n < 4; ++n)
      bf[n] = *(const f16x8*)&sb[(brow + n * 16) * 64 + xo1];
    asm volatile("s_waitcnt lgkmcnt(0)" ::: "memory");
    __builtin_amdgcn_sched_barrier(0);
    __builtin_amdgcn_s_barrier();  // all waves done reading slot rb
    if (t + 2 < nt) stage(rb, (t + 2) * 64);
    __builtin_amdgcn_s_setprio(1);
#pragma unroll
    for (int m = 0; m < 2; ++m)
#pragma unroll
      for (int n = 0; n < 4; ++n)
        acc[m][n] = __builtin_amdgcn_mfma_f32_16x16x32_f16(af[m], bf[n],
                                                           acc[m][n], 0, 0, 0);
    __builtin_amdgcn_s_setprio(0);
    __builtin_amdgcn_s_barrier();
    rb ^= 1;
  }

  // epilogue: divide by row sum, f32 store
  float li[2][4];
#pragma unroll
  for (int m = 0; m < 2; ++m)
#pragma unroll
    for (int jj = 0; jj < 4; ++jj)
      li[m][jj] = 1.0f / L[bm * 64 + wm * 32 + m * 16 + g * 4 + jj];
#pragma unroll
  for (int m = 0; m < 2; ++m)
#pragma unroll
    for (int n = 0; n < 4; ++n)
#pragma unroll
      for (int jj = 0; jj < 4; ++jj) {
        int row = bm * 64 + wm * 32 + m * 16 + g * 4 + jj;
        int col = bn * 256 + wn * 64 + n * 16 + r;
        C[(long)row * OO + col] = acc[m][n][jj] * li[m][jj];
      }
}

// ---------------------------------------------------------------------------
extern "C" void kernel_launch(void* const* d_in, const int* in_sizes, int n_in,
                              void* d_out, int out_size, void* d_ws,
                              size_t ws_size, hipStream_t stream) {
  const float* X = (const float*)d_in[0];
  const float* WQ = (const float*)d_in[1];
  const float* WK = (const float*)d_in[2];
  const float* WV = (const float*)d_in[3];
  float* out = (float*)d_out;

  char* ws = (char*)d_ws;
  f16* Xh = (f16*)ws;                    // 8192x1024 f16 = 16 MB
  f16* Wt = (f16*)(ws + 16777216);       // 3 x [512][1024] f16 = 3 MB (Q,K,V)
  f16* QKh = (f16*)(ws + 19922944);      // 8192x1024 f16 = 16 MB (Q|K cols)
  f16* Vt = (f16*)(ws + 36700160);       // 4 x [512][2048] f16 = 8 MB
  f16* Pb = (f16*)(ws + 45088768);       // 4 x 2048x2048 f16 = 33.5 MB
  float* Ls = (float*)(ws + 78643200);   // 4 x 2048 f32 = 32 KB

  const float kScale = 0.044194173824159216f;  // 1/sqrt(512)
  const float kSclLog2e = kScale * 1.4426950408889634f;
  const float kShift = 12.0f * 1.4426950408889634f;

  // 1) prep: convert X, transpose-convert W, zero Ls
  prep<<<4512, 256, 0, stream>>>(X, Xh, WQ, WK, WV, Wt, Ls);
  // 2) merged QK (one N=1024 GEMM) + V^T projections
  proj_qkv<<<768, 256, 0, stream>>>(Xh, Wt, QKh, Vt);
  // 3) scores+exp (256x256, 8 waves, 8-phase) + rowsum atomics
  scores256<<<256, 512, 0, stream>>>(QKh, Pb, Ls, kSclLog2e, kShift);
  // 4) out = (P~ @ V) / Ls[row]  (64x256, 8 waves, phase sched)
  pv256<<<256, 512, 0, stream>>>(Pb, Vt, out, Ls);
}

// Round 8
// 103.333 us; speedup vs baseline: 1.0058x; 1.0058x over previous
//
#include <hip/hip_runtime.h>
#include <hip/hip_bf16.h>
#include <hip/hip_fp16.h>

typedef _Float16 f16;
typedef _Float16 f16x8 __attribute__((ext_vector_type(8)));
typedef float f32x4 __attribute__((ext_vector_type(4)));

#define NB 4
#define SS 2048
#define DD 1024
#define OO 512

// ---- prep: cvt X f32->f16 | transpose-cvt W | zero Ls  (flat grid 4512) ---
__global__ __launch_bounds__(256) void prep(const float* __restrict__ X,
                                            f16* __restrict__ Xh,
                                            const float* __restrict__ w0,
                                            const float* __restrict__ w1,
                                            const float* __restrict__ w2,
                                            f16* __restrict__ Wt,
                                            float* __restrict__ Ls) {
  int b = blockIdx.x;
  int tid = threadIdx.x;
  if (b < 4096) {
    int i = b * 256 + tid;
    const float4* xp = (const float4*)X + (size_t)i * 2;
    float4 a = xp[0], c = xp[1];
    f16x8 v;
    v[0] = (f16)a.x; v[1] = (f16)a.y; v[2] = (f16)a.z; v[3] = (f16)a.w;
    v[4] = (f16)c.x; v[5] = (f16)c.y; v[6] = (f16)c.z; v[7] = (f16)c.w;
    *((f16x8*)Xh + i) = v;
  } else if (b < 4480) {
    int rem = b - 4096;                 // 0..383
    int z = rem >> 7;                   // 0..2
    int rem2 = rem & 127;
    int d0 = (rem2 >> 3) * 64;          // 0..15 -> D blocks
    int o0 = (rem2 & 7) * 64;           // 0..7  -> O blocks
    const float* w = z == 0 ? w0 : (z == 1 ? w1 : w2);
    f16* out = Wt + (size_t)z * OO * DD;
    __shared__ float t[64][65];
#pragma unroll
    for (int i = 0; i < 16; ++i) {
      int idx = i * 256 + tid;
      int r = idx >> 6, c = idx & 63;
      t[r][c] = w[(size_t)(d0 + r) * OO + (o0 + c)];
    }
    __syncthreads();
#pragma unroll
    for (int i = 0; i < 16; ++i) {
      int idx = i * 256 + tid;
      int r = idx >> 6, c = idx & 63;
      out[(size_t)(o0 + r) * DD + (d0 + c)] = (f16)t[c][r];
    }
  } else {
    Ls[(b - 4480) * 256 + tid] = 0.f;
  }
}

// --------------- async global -> LDS, 16B per lane ------------------------
__device__ __forceinline__ void gload_lds16(const f16* g, f16* l) {
  __builtin_amdgcn_global_load_lds(
      (const __attribute__((address_space(1))) void*)g,
      (__attribute__((address_space(3))) void*)l, 16, 0, 0);
}

// counted vmcnt wait: leave fut*LPI loads outstanding (immediates only)
template <int LPI>
__device__ __forceinline__ void wait_fut(int fut) {
  if constexpr (LPI == 6) {  // TM=64, RING=3
    if (fut >= 2) asm volatile("s_waitcnt vmcnt(12)" ::: "memory");
    else if (fut == 1) asm volatile("s_waitcnt vmcnt(6)" ::: "memory");
    else asm volatile("s_waitcnt vmcnt(0)" ::: "memory");
  } else {  // LPI==8: RING=2
    if (fut >= 1) asm volatile("s_waitcnt vmcnt(8)" ::: "memory");
    else asm volatile("s_waitcnt vmcnt(0)" ::: "memory");
  }
}

// ---- 256x256 8-wave 4-phase GEMM body (validated skeleton) ----------------
// acc[8][4]: wave (wm,wn) owns rows wm*128..+128, cols wn*64..+64.
__device__ __forceinline__ void body256(const f16* __restrict__ Ag,
                                        const f16* __restrict__ Bg, int lda,
                                        int ldb, int nt, f32x4 (&acc)[8][4]) {
  __shared__ f16 ring[2 * 32768];  // 128 KB
  int tid = threadIdx.x;
  int lane = tid & 63, wid = tid >> 6;
  int wm = wid >> 2, wn = wid & 3;  // 2M x 4N waves
  int r = lane & 15, g = lane >> 4;
  int srow = tid >> 3;  // 0..63
  int scol = (((tid & 7) ^ ((tid >> 3) & 7)) << 3);

  auto stage = [&](int si, int k0) {
    f16* s = ring + si * 32768;
#pragma unroll
    for (int i = 0; i < 4; ++i)
      gload_lds16(Ag + (long)(i * 64 + srow) * lda + k0 + scol,
                  s + i * 4096 + tid * 8);
#pragma unroll
    for (int i = 0; i < 4; ++i)
      gload_lds16(Bg + (long)(i * 64 + srow) * ldb + k0 + scol,
                  s + 16384 + i * 4096 + tid * 8);
  };
  stage(0, 0);
  stage(1, 64);

  int rb = 0;
  int arow = wm * 128 + r, brow = wn * 64 + r;
  for (int t = 0; t < nt; ++t) {
    if (t < nt - 1) asm volatile("s_waitcnt vmcnt(8)" ::: "memory");
    else            asm volatile("s_waitcnt vmcnt(0)" ::: "memory");
    __builtin_amdgcn_s_barrier();
    const f16* sa = ring + rb * 32768;
    const f16* sb = sa + 16384;
    int xo0 = ((g * 16) ^ ((r & 7) << 4)) >> 1;
    int xo1 = ((64 + g * 16) ^ ((r & 7) << 4)) >> 1;
    f16x8 af[4], bf[4];
    // ---- phase 0: m0-3, kk=0 ----
#pragma unroll
    for (int m = 0; m < 4; ++m)
      af[m] = *(const f16x8*)&sa[(arow + m * 16) * 64 + xo0];
#pragma unroll
    for (int n = 0; n < 4; ++n)
      bf[n] = *(const f16x8*)&sb[(brow + n * 16) * 64 + xo0];
    __builtin_amdgcn_s_barrier();
    asm volatile("s_waitcnt lgkmcnt(0)" ::: "memory");
    __builtin_amdgcn_sched_barrier(0);
    __builtin_amdgcn_s_setprio(1);
#pragma unroll
    for (int m = 0; m < 4; ++m)
#pragma unroll
      for (int n = 0; n < 4; ++n)
        acc[m][n] = __builtin_amdgcn_mfma_f32_16x16x32_f16(af[m], bf[n],
                                                           acc[m][n], 0, 0, 0);
    __builtin_amdgcn_s_setprio(0);
    __builtin_amdgcn_s_barrier();
    // ---- phase 1: m4-7, kk=0 ----
#pragma unroll
    for (int m = 0; m < 4; ++m)
      af[m] = *(const f16x8*)&sa[(arow + (m + 4) * 16) * 64 + xo0];
    __builtin_amdgcn_s_barrier();
    asm volatile("s_waitcnt lgkmcnt(0)" ::: "memory");
    __builtin_amdgcn_sched_barrier(0);
    __builtin_amdgcn_s_setprio(1);
#pragma unroll
    for (int m = 0; m < 4; ++m)
#pragma unroll
      for (int n = 0; n < 4; ++n)
        acc[m + 4][n] = __builtin_amdgcn_mfma_f32_16x16x32_f16(
            af[m], bf[n], acc[m + 4][n], 0, 0, 0);
    __builtin_amdgcn_s_setprio(0);
    __builtin_amdgcn_s_barrier();
    // ---- phase 2: m0-3, kk=32 ----
#pragma unroll
    for (int m = 0; m < 4; ++m)
      af[m] = *(const f16x8*)&sa[(arow + m * 16) * 64 + xo1];
#pragma unroll
    for (int n = 0; n < 4; ++n)
      bf[n] = *(const f16x8*)&sb[(brow + n * 16) * 64 + xo1];
    __builtin_amdgcn_s_barrier();
    asm volatile("s_waitcnt lgkmcnt(0)" ::: "memory");
    __builtin_amdgcn_sched_barrier(0);
    __builtin_amdgcn_s_setprio(1);
#pragma unroll
    for (int m = 0; m < 4; ++m)
#pragma unroll
      for (int n = 0; n < 4; ++n)
        acc[m][n] = __builtin_amdgcn_mfma_f32_16x16x32_f16(af[m], bf[n],
                                                           acc[m][n], 0, 0, 0);
    __builtin_amdgcn_s_setprio(0);
    __builtin_amdgcn_s_barrier();
    // ---- phase 3: m4-7, kk=32; stage t+2 after read-complete barrier ----
#pragma unroll
    for (int m = 0; m < 4; ++m)
      af[m] = *(const f16x8*)&sa[(arow + (m + 4) * 16) * 64 + xo1];
    asm volatile("s_waitcnt lgkmcnt(0)" ::: "memory");
    __builtin_amdgcn_sched_barrier(0);
    __builtin_amdgcn_s_barrier();  // all waves done reading slot rb
    if (t + 2 < nt) stage(rb, (t + 2) * 64);
    __builtin_amdgcn_s_setprio(1);
#pragma unroll
    for (int m = 0; m < 4; ++m)
#pragma unroll
      for (int n = 0; n < 4; ++n)
        acc[m + 4][n] = __builtin_amdgcn_mfma_f32_16x16x32_f16(
            af[m], bf[n], acc[m + 4][n], 0, 0, 0);
    __builtin_amdgcn_s_setprio(0);
    __builtin_amdgcn_s_barrier();
    rb ^= 1;
  }
}

// ---- proj256: QK proj (128 blocks) + V proj (64 blocks), 256^2 tiles ------
__global__ __launch_bounds__(512) void proj256(const f16* __restrict__ Xh,
                                               const f16* __restrict__ Wt,
                                               f16* __restrict__ QKh,
                                               f16* __restrict__ Vt) {
  int id = blockIdx.x;
  const f16 *Ag, *Bg;
  f16* C;
  int ldc;
  if (id < 128) {  // QK: Xh[8192,1024] @ Wt[0:1024]^T -> QKh[8192,1024]
    int x = id & 7, j = id >> 3;  // XCD x: bm in [4x,4x+4), all bn
    int bm = x * 4 + (j >> 2);    // [0,32)
    int bn = j & 3;               // [0,4)
    Ag = Xh + (long)bm * 256 * DD;
    Bg = Wt + (long)bn * 256 * DD;
    C = QKh + (long)bm * 256 * 1024 + bn * 256;
    ldc = 1024;
  } else {  // V: WtV[512,1024] @ Xh_z^T -> Vt[z][512][2048]
    int vid = id - 128;           // [0,64)
    int x = vid & 7, j = vid >> 3;
    int z = j >> 1;               // [0,4)
    int bm = j & 1;               // [0,2)
    int bn = x;                   // [0,8), pinned per XCD
    Ag = Wt + 2L * OO * DD + (long)bm * 256 * DD;
    Bg = Xh + (long)z * SS * DD + (long)bn * 256 * DD;
    C = Vt + (long)z * OO * SS + (long)bm * 256 * SS + bn * 256;
    ldc = SS;
  }
  f32x4 acc[8][4] = {};
  body256(Ag, Bg, DD, DD, 16, acc);

  int lane = threadIdx.x & 63, wid = threadIdx.x >> 6;
  int wm = wid >> 2, wn = wid & 3;
  int r = lane & 15, g = lane >> 4;
#pragma unroll
  for (int m = 0; m < 8; ++m)
#pragma unroll
    for (int n = 0; n < 4; ++n)
#pragma unroll
      for (int j = 0; j < 4; ++j) {
        int row = wm * 128 + m * 16 + g * 4 + j;
        int col = wn * 64 + n * 16 + r;
        C[(long)row * ldc + col] = (f16)acc[m][n][j];
      }
}

// ---- scores256: P~ = exp2(QK^T*scl - shift) -> f16, rowsums -> Ls ---------
__global__ __launch_bounds__(512) void scores256(const f16* __restrict__ QKh,
                                                 f16* __restrict__ P,
                                                 float* __restrict__ L,
                                                 float scale, float shift) {
  int b = blockIdx.x;                // [0,256) flat, XCD = b%8
  int x = b & 7, j = b >> 3;         // j in [0,32)
  int z = x >> 1;                    // 2 XCDs per batch
  int bm = (x & 1) * 4 + (j >> 3);   // [0,8)
  int bn = j & 7;                    // [0,8)

  const f16* Ag = QKh + (long)z * SS * 1024 + (long)(bm * 256) * 1024;
  const f16* Bg = QKh + (long)z * SS * 1024 + 512 + (long)(bn * 256) * 1024;
  f16* C = P + (long)z * SS * SS;
  float* Ls = L + (long)z * SS;

  f32x4 acc[8][4] = {};
  body256(Ag, Bg, 1024, 1024, 8, acc);

  int lane = threadIdx.x & 63, wid = threadIdx.x >> 6;
  int wm = wid >> 2, wn = wid & 3;
  int r = lane & 15, g = lane >> 4;
  float rs[8][4];
#pragma unroll
  for (int m = 0; m < 8; ++m)
#pragma unroll
    for (int jj = 0; jj < 4; ++jj) rs[m][jj] = 0.f;
#pragma unroll
  for (int m = 0; m < 8; ++m)
#pragma unroll
    for (int n = 0; n < 4; ++n)
#pragma unroll
      for (int jj = 0; jj < 4; ++jj) {
        int row = bm * 256 + wm * 128 + m * 16 + g * 4 + jj;
        int col = bn * 256 + wn * 64 + n * 16 + r;
        float e = exp2f(acc[m][n][jj] * scale - shift);
        C[(long)row * SS + col] = (f16)e;
        rs[m][jj] += e;
      }
#pragma unroll
  for (int m = 0; m < 8; ++m)
#pragma unroll
    for (int jj = 0; jj < 4; ++jj) {
      float v = rs[m][jj];
      v += __shfl_xor(v, 1);
      v += __shfl_xor(v, 2);
      v += __shfl_xor(v, 4);
      v += __shfl_xor(v, 8);
      if (r == 0)
        atomicAdd(&Ls[bm * 256 + wm * 128 + m * 16 + g * 4 + jj], v);
    }
}

// ---- PV GEMM body: 64x128 tile, BK=64, 4 waves, RING=3 (R5-validated) -----
__global__ __launch_bounds__(256) void pv(const f16* __restrict__ Pb,
                                          const f16* __restrict__ Vt,
                                          float* __restrict__ out,
                                          const float* __restrict__ Ls) {
  int b = blockIdx.x;               // [0,512) flat, XCD = b%8
  int x = b & 7, k = b >> 3;        // k in [0,64)
  int z = x >> 1;                   // 2 XCDs per batch
  int bm = (x & 1) * 16 + (k >> 2); // [0,32)
  int bn = k & 3;                   // [0,4)

  const f16* A = Pb + (long)z * SS * SS;
  const f16* B = Vt + (long)z * OO * SS;
  float* C = out + (long)z * SS * OO;
  const float* L = Ls + (long)z * SS;

  constexpr int TM = 64, RING = 3, MF = 2;
  constexpr int SLOT = (TM + 128) * 64;
  __shared__ f16 ring[RING * SLOT];

  int tid = threadIdx.x;
  int lane = tid & 63, wid = tid >> 6;
  int wr = (wid >> 1) * (MF * 16), wc = (wid & 1) << 6;
  int r = lane & 15, g = lane >> 4;

  const f16* Ag = A + (long)(bm * TM) * SS;
  const f16* Bg = B + (long)(bn * 128) * SS;

  int srow = wid * 8 + (lane >> 3);
  int scol = (((lane & 7) ^ ((lane >> 3) & 7)) << 3);

  f32x4 acc[MF][4] = {};
  const int nt = SS >> 6;  // 32

  auto stage = [&](int si, int k0) {
    f16* s = ring + si * SLOT;
#pragma unroll
    for (int i = 0; i < TM / 32; ++i)
      gload_lds16(Ag + (long)(i * 32 + srow) * SS + k0 + scol,
                  s + i * 2048 + wid * 512);
#pragma unroll
    for (int i = 0; i < 4; ++i)
      gload_lds16(Bg + (long)(i * 32 + srow) * SS + k0 + scol,
                  s + TM * 64 + i * 2048 + wid * 512);
  };

  for (int p = 0; p < RING && p < nt; ++p) stage(p, p * 64);

  int rb = 0;
  for (int t = 0; t < nt; ++t) {
    int fut = nt - 1 - t;
    if (fut > RING - 1) fut = RING - 1;
    wait_fut<6>(fut);
    __builtin_amdgcn_s_barrier();
    __builtin_amdgcn_sched_barrier(0);
    const f16* sa = ring + rb * SLOT;
    const f16* sb = sa + TM * 64;
#pragma unroll
    for (int kk = 0; kk < 64; kk += 32) {
      f16x8 af[MF], bf[4];
      int xo = ((kk * 2 + g * 16) ^ ((r & 7) << 4)) >> 1;
#pragma unroll
      for (int m = 0; m < MF; ++m)
        af[m] = *(const f16x8*)&sa[(wr + m * 16 + r) * 64 + xo];
#pragma unroll
      for (int n = 0; n < 4; ++n)
        bf[n] = *(const f16x8*)&sb[(wc + n * 16 + r) * 64 + xo];
#pragma unroll
      for (int m = 0; m < MF; ++m)
#pragma unroll
        for (int n = 0; n < 4; ++n)
          acc[m][n] = __builtin_amdgcn_mfma_f32_16x16x32_f16(af[m], bf[n],
                                                             acc[m][n], 0, 0, 0);
    }
    __builtin_amdgcn_s_barrier();
    __builtin_amdgcn_sched_barrier(0);
    if (t + RING < nt) stage(rb, (t + RING) * 64);
    rb = (rb + 1 == RING) ? 0 : rb + 1;
  }

  float li[MF][4];
#pragma unroll
  for (int m = 0; m < MF; ++m)
#pragma unroll
    for (int j = 0; j < 4; ++j)
      li[m][j] = 1.0f / L[bm * TM + wr + m * 16 + g * 4 + j];
#pragma unroll
  for (int m = 0; m < MF; ++m)
#pragma unroll
    for (int n = 0; n < 4; ++n)
#pragma unroll
      for (int j = 0; j < 4; ++j) {
        int row = bm * TM + wr + m * 16 + g * 4 + j;
        int col = bn * 128 + wc + n * 16 + r;
        C[(long)row * OO + col] = acc[m][n][j] * li[m][j];
      }
}

// ---------------------------------------------------------------------------
extern "C" void kernel_launch(void* const* d_in, const int* in_sizes, int n_in,
                              void* d_out, int out_size, void* d_ws,
                              size_t ws_size, hipStream_t stream) {
  const float* X = (const float*)d_in[0];
  const float* WQ = (const float*)d_in[1];
  const float* WK = (const float*)d_in[2];
  const float* WV = (const float*)d_in[3];
  float* out = (float*)d_out;

  char* ws = (char*)d_ws;
  f16* Xh = (f16*)ws;                    // 8192x1024 f16 = 16 MB
  f16* Wt = (f16*)(ws + 16777216);       // 3 x [512][1024] f16 = 3 MB (Q,K,V)
  f16* QKh = (f16*)(ws + 19922944);      // 8192x1024 f16 = 16 MB (Q|K cols)
  f16* Vt = (f16*)(ws + 36700160);       // 4 x [512][2048] f16 = 8 MB
  f16* Pb = (f16*)(ws + 45088768);       // 4 x 2048x2048 f16 = 33.5 MB
  float* Ls = (float*)(ws + 78643200);   // 4 x 2048 f32 = 32 KB

  const float kScale = 0.044194173824159216f;  // 1/sqrt(512)
  const float kSclLog2e = kScale * 1.4426950408889634f;
  const float kShift = 12.0f * 1.4426950408889634f;

  // 1) prep: convert X, transpose-convert W, zero Ls
  prep<<<4512, 256, 0, stream>>>(X, Xh, WQ, WK, WV, Wt, Ls);
  // 2) QK (256^2 x128 blocks) + V (256^2 x64 blocks) projections
  proj256<<<192, 512, 0, stream>>>(Xh, Wt, QKh, Vt);
  // 3) scores+exp (256x256, 8 waves, 4-phase) + rowsum atomics
  scores256<<<256, 512, 0, stream>>>(QKh, Pb, Ls, kSclLog2e, kShift);
  // 4) out = (P~ @ V) / Ls[row]  (64x128, 4 waves, RING=3)
  pv<<<512, 256, 0, stream>>>(Pb, Vt, out, Ls);
}